// Round 1
// baseline (464.937 us; speedup 1.0000x reference)
//
#include <hip/hip_runtime.h>
#include <hip/hip_bf16.h>
#include <stdint.h>

#define IN_F   4096
#define OUT_F  4096
#define BATCHN 8192

#define BM 128
#define BN 128
#define BK 32
#define NT_N (OUT_F / BN)   // 32 column tiles
#define NT_M (BATCHN / BM)  // 64 row tiles

using f32x4 = __attribute__((ext_vector_type(4))) float;
using f16x8 = __attribute__((ext_vector_type(8))) _Float16;
using i32x4 = __attribute__((ext_vector_type(4))) int;
using u32x4 = __attribute__((ext_vector_type(4))) unsigned int;

__device__ __forceinline__ void gload_lds16(const void* g, void* l) {
    __builtin_amdgcn_global_load_lds(
        (const __attribute__((address_space(1))) void*)g,
        (__attribute__((address_space(3))) void*)l,
        16, 0, 0);
}

__device__ __forceinline__ u32x4 pack8_f16(const float* v) {
    union { _Float16 h[8]; u32x4 u; } p;
#pragma unroll
    for (int i = 0; i < 8; ++i) p.h[i] = (_Float16)v[i];
    return p.u;
}

// ---------------------------------------------------------------------------
// Kernel 1: W[o][i] = h_weight[idxW[o][i]] * xiW[o][i]  -> fp16, row-major
// 8 elements per thread. 16M elems -> 8192 blocks x 256 threads.
// ---------------------------------------------------------------------------
__global__ __launch_bounds__(256) void build_w(const float* __restrict__ hw,
                                               const float* __restrict__ xi,
                                               const int*   __restrict__ idx,
                                               u32x4* __restrict__ Wh) {
    size_t t = (size_t)blockIdx.x * 256 + threadIdx.x;
    size_t base = t * 8;
    i32x4 i0 = *(const i32x4*)(idx + base);
    i32x4 i1 = *(const i32x4*)(idx + base + 4);
    f32x4 s0 = *(const f32x4*)(xi + base);
    f32x4 s1 = *(const f32x4*)(xi + base + 4);
    float v[8];
    v[0] = hw[i0[0]] * s0[0];
    v[1] = hw[i0[1]] * s0[1];
    v[2] = hw[i0[2]] * s0[2];
    v[3] = hw[i0[3]] * s0[3];
    v[4] = hw[i1[0]] * s1[0];
    v[5] = hw[i1[1]] * s1[1];
    v[6] = hw[i1[2]] * s1[2];
    v[7] = hw[i1[3]] * s1[3];
    Wh[t] = pack8_f16(v);
}

// ---------------------------------------------------------------------------
// Kernel 2: x fp32 -> fp16. 33.5M elems, 8/thread -> 16384 blocks.
// ---------------------------------------------------------------------------
__global__ __launch_bounds__(256) void conv_x(const float* __restrict__ x,
                                              u32x4* __restrict__ Xh) {
    size_t t = (size_t)blockIdx.x * 256 + threadIdx.x;
    size_t base = t * 8;
    f32x4 a = *(const f32x4*)(x + base);
    f32x4 b = *(const f32x4*)(x + base + 4);
    float v[8] = {a[0], a[1], a[2], a[3], b[0], b[1], b[2], b[3]};
    Xh[t] = pack8_f16(v);
}

// ---------------------------------------------------------------------------
// Kernel 3: bias[o] = h_bias[idxB[o]] * xiB[o]  (fp32)
// ---------------------------------------------------------------------------
__global__ __launch_bounds__(256) void build_bias(const float* __restrict__ hb,
                                                  const float* __restrict__ xib,
                                                  const int*   __restrict__ idxb,
                                                  float* __restrict__ bias) {
    int o = blockIdx.x * 256 + threadIdx.x;
    if (o < OUT_F) bias[o] = hb[idxb[o]] * xib[o];
}

// ---------------------------------------------------------------------------
// Kernel 4: C[b][o] = sum_k Xh[b][k]*Wh[o][k] + bias[o]
// m97-structure: 128x128 tile, BK=32, 4 waves (2x2), 4x4 16x16x32 frags/wave,
// global_load_lds width-16 staging, 2 barriers per K-step.
// ---------------------------------------------------------------------------
__global__ __launch_bounds__(256) void gemm_bt(const _Float16* __restrict__ A, // [BATCHN][IN_F]
                                               const _Float16* __restrict__ B, // [OUT_F][IN_F]
                                               const float*    __restrict__ bias,
                                               float*          __restrict__ C) {
    __shared__ _Float16 As[BM][BK]; // 8 KB
    __shared__ _Float16 Bs[BN][BK]; // 8 KB

    const int tid  = threadIdx.x;
    const int wave = tid >> 6;
    const int lane = tid & 63;
    const int wr   = wave >> 1;   // 0..1: wave row (64 rows each)
    const int wc   = wave & 1;    // 0..1: wave col (64 cols each)

    // XCD-aware bijective swizzle: nwg = 2048, divisible by 8.
    const int bid = blockIdx.x;
    const int cpx = (NT_M * NT_N) >> 3; // 256
    const int swz = (bid & 7) * cpx + (bid >> 3);
    const int m_idx = swz / NT_N;
    const int n_idx = swz % NT_N;
    const size_t brow = (size_t)m_idx * BM;
    const size_t bcol = (size_t)n_idx * BN;

    // staging: thread t loads 16B (8 fp16): row = t>>2 (+64), col = (t&3)*8
    const int sr = tid >> 2;
    const int sc = (tid & 3) * 8;
    const _Float16* gA0 = A + (brow + sr) * IN_F + sc;
    const _Float16* gA1 = gA0 + (size_t)64 * IN_F;
    const _Float16* gB0 = B + (bcol + sr) * IN_F + sc;
    const _Float16* gB1 = gB0 + (size_t)64 * IN_F;
    _Float16* lA0 = &As[sr][sc];
    _Float16* lA1 = &As[sr + 64][sc];
    _Float16* lB0 = &Bs[sr][sc];
    _Float16* lB1 = &Bs[sr + 64][sc];

    f32x4 acc[4][4];
#pragma unroll
    for (int m = 0; m < 4; ++m)
#pragma unroll
        for (int n = 0; n < 4; ++n) acc[m][n] = (f32x4){0.f, 0.f, 0.f, 0.f};

    // fragment addresses: A row = wr*64 + m*16 + (lane&15), k = (lane>>4)*8
    const int frow_a = wr * 64 + (lane & 15);
    const int frow_b = wc * 64 + (lane & 15);
    const int kk = (lane >> 4) * 8;

    for (int k0 = 0; k0 < IN_F; k0 += BK) {
        gload_lds16(gA0, lA0);
        gload_lds16(gA1, lA1);
        gload_lds16(gB0, lB0);
        gload_lds16(gB1, lB1);
        gA0 += BK; gA1 += BK; gB0 += BK; gB1 += BK;
        __syncthreads();

        f16x8 af[4], bf[4];
#pragma unroll
        for (int m = 0; m < 4; ++m)
            af[m] = *(const f16x8*)&As[frow_a + m * 16][kk];
#pragma unroll
        for (int n = 0; n < 4; ++n)
            bf[n] = *(const f16x8*)&Bs[frow_b + n * 16][kk];

#pragma unroll
        for (int m = 0; m < 4; ++m)
#pragma unroll
            for (int n = 0; n < 4; ++n)
                acc[m][n] = __builtin_amdgcn_mfma_f32_16x16x32_f16(
                    af[m], bf[n], acc[m][n], 0, 0, 0);
        __syncthreads();
    }

    // epilogue: C/D layout col = lane&15, row = (lane>>4)*4 + j
    const int crow0 = (lane >> 4) * 4;
    const int ccol0 = lane & 15;
#pragma unroll
    for (int n = 0; n < 4; ++n) {
        const size_t col = bcol + wc * 64 + n * 16 + ccol0;
        const float bv = bias[col];
#pragma unroll
        for (int m = 0; m < 4; ++m) {
            const size_t row = brow + wr * 64 + m * 16 + crow0;
#pragma unroll
            for (int j = 0; j < 4; ++j)
                C[(row + j) * OUT_F + col] = acc[m][n][j] + bv;
        }
    }
}

// ---------------------------------------------------------------------------
extern "C" void kernel_launch(void* const* d_in, const int* in_sizes, int n_in,
                              void* d_out, int out_size, void* d_ws, size_t ws_size,
                              hipStream_t stream) {
    const float* x    = (const float*)d_in[0];
    const float* hw   = (const float*)d_in[1];
    const float* hb   = (const float*)d_in[2];
    const float* xiW  = (const float*)d_in[3];
    const float* xiB  = (const float*)d_in[4];
    const int*   idxW = (const int*)d_in[5];
    const int*   idxB = (const int*)d_in[6];
    float* out = (float*)d_out;

    char* ws = (char*)d_ws;
    _Float16* Wh  = (_Float16*)ws;                                   // 32 MB
    _Float16* Xh  = (_Float16*)(ws + (size_t)32 * 1024 * 1024);      // 64 MB
    float*    bia = (float*)   (ws + (size_t)96 * 1024 * 1024);      // 16 KB

    // 1. materialize dense W (fp16): 16M elems / 8 per thread / 256 = 8192 blocks
    build_w<<<8192, 256, 0, stream>>>(hw, xiW, idxW, (u32x4*)Wh);
    // 2. x -> fp16: 33.5M elems / 8 / 256 = 16384 blocks
    conv_x<<<16384, 256, 0, stream>>>(x, (u32x4*)Xh);
    // 3. bias
    build_bias<<<OUT_F / 256, 256, 0, stream>>>(hb, xiB, idxB, bia);
    // 4. GEMM: 64 x 32 tiles = 2048 blocks
    gemm_bt<<<NT_M * NT_N, 256, 0, stream>>>(Xh, Wh, bia, out);
}

// Round 2
// 383.598 us; speedup vs baseline: 1.2120x; 1.2120x over previous
//
#include <hip/hip_runtime.h>
#include <hip/hip_bf16.h>
#include <stdint.h>

#define IN_F   4096
#define OUT_F  4096
#define BATCHN 8192

#define BK   64
#define NTK  (IN_F / BK)       // 64 K-tiles
#define HOFF (128 * IN_F)      // half-tile (128 rows) offset in elements

using f32x4 = __attribute__((ext_vector_type(4))) float;
using f16x8 = __attribute__((ext_vector_type(8))) _Float16;
using i32x4 = __attribute__((ext_vector_type(4))) int;
using u32x4 = __attribute__((ext_vector_type(4))) unsigned int;

__device__ __forceinline__ void stg(const _Float16* src, int kelem, char* sm, int dstoff) {
    __builtin_amdgcn_global_load_lds(
        (const __attribute__((address_space(1))) void*)(src + kelem),
        (__attribute__((address_space(3))) void*)(sm + dstoff), 16, 0, 0);
}

__device__ __forceinline__ u32x4 pack8_f16(const float* v) {
    union { _Float16 h[8]; u32x4 u; } p;
#pragma unroll
    for (int i = 0; i < 8; ++i) p.h[i] = (_Float16)v[i];
    return p.u;
}

// ---------------------------------------------------------------------------
// Kernel 1: W[o][i] = h_weight[idxW[o][i]] * xiW[o][i]  -> fp16, row-major
// ---------------------------------------------------------------------------
__global__ __launch_bounds__(256) void build_w(const float* __restrict__ hw,
                                               const float* __restrict__ xi,
                                               const int*   __restrict__ idx,
                                               u32x4* __restrict__ Wh) {
    size_t t = (size_t)blockIdx.x * 256 + threadIdx.x;
    size_t base = t * 8;
    i32x4 i0 = *(const i32x4*)(idx + base);
    i32x4 i1 = *(const i32x4*)(idx + base + 4);
    f32x4 s0 = *(const f32x4*)(xi + base);
    f32x4 s1 = *(const f32x4*)(xi + base + 4);
    float v[8];
    v[0] = hw[i0[0]] * s0[0];
    v[1] = hw[i0[1]] * s0[1];
    v[2] = hw[i0[2]] * s0[2];
    v[3] = hw[i0[3]] * s0[3];
    v[4] = hw[i1[0]] * s1[0];
    v[5] = hw[i1[1]] * s1[1];
    v[6] = hw[i1[2]] * s1[2];
    v[7] = hw[i1[3]] * s1[3];
    Wh[t] = pack8_f16(v);
}

// ---------------------------------------------------------------------------
// Kernel 2: x fp32 -> fp16
// ---------------------------------------------------------------------------
__global__ __launch_bounds__(256) void conv_x(const float* __restrict__ x,
                                              u32x4* __restrict__ Xh) {
    size_t t = (size_t)blockIdx.x * 256 + threadIdx.x;
    size_t base = t * 8;
    f32x4 a = *(const f32x4*)(x + base);
    f32x4 b = *(const f32x4*)(x + base + 4);
    float v[8] = {a[0], a[1], a[2], a[3], b[0], b[1], b[2], b[3]};
    Xh[t] = pack8_f16(v);
}

// ---------------------------------------------------------------------------
// Kernel 3: bias[o] = h_bias[idxB[o]] * xiB[o]
// ---------------------------------------------------------------------------
__global__ __launch_bounds__(256) void build_bias(const float* __restrict__ hb,
                                                  const float* __restrict__ xib,
                                                  const int*   __restrict__ idxb,
                                                  float* __restrict__ bias) {
    int o = blockIdx.x * 256 + threadIdx.x;
    if (o < OUT_F) bias[o] = hb[idxb[o]] * xib[o];
}

// ---------------------------------------------------------------------------
// Kernel 4: 256x256x64 8-phase-style GEMM, fp16 MFMA, fp32 out + bias.
// LDS: 2 buffers x (A 32KB + B 32KB) = 128KB dynamic.
// Swizzle: phys_byte = linear_byte ^ ((row&7)<<4) (both-sides: inverse on
// global source for global_load_lds, forward on ds_read addresses).
// Per K-tile: 4 phases, each {ds_read | stage half-tile | barrier | 16 MFMA
// (setprio) | barrier}; one counted vmcnt(4) per tile at phase 3.
// ---------------------------------------------------------------------------
__global__ __launch_bounds__(512, 2) void gemm_8ph(const _Float16* __restrict__ A,  // [BATCHN][IN_F]
                                                   const _Float16* __restrict__ Bm, // [OUT_F][IN_F]
                                                   const float*    __restrict__ bias,
                                                   float*          __restrict__ C) {
    extern __shared__ char smem[];
    const int tid  = threadIdx.x;
    const int lane = tid & 63;
    const int wave = tid >> 6;
    const int wr   = wave >> 2;  // 0..1 -> rows wr*128
    const int wc   = wave & 3;   // 0..3 -> cols wc*64

    // XCD-aware bijective swizzle (512 blocks, 512%8==0). m fastest within
    // an XCD chunk so resident blocks share one B panel (L2-fit).
    const int bid = blockIdx.x;
    const int swz = ((bid & 7) << 6) | (bid >> 3);
    const int m_idx = swz & 31;
    const int n_idx = swz >> 5;
    const size_t brow = (size_t)m_idx * 256;
    const size_t bcol = (size_t)n_idx * 256;

    // --- staging source addresses (inverse-swizzled global side) ---
    const int srow = tid >> 3;                       // 0..63
    const int scol = ((tid & 7) ^ (srow & 7)) << 3;  // element col (inverse XOR)
    const _Float16* aS0 = A  + (brow + srow)      * IN_F + scol;  // j=0 rows
    const _Float16* aS1 = A  + (brow + 64 + srow) * IN_F + scol;  // j=1 rows
    const _Float16* bS0 = Bm + (bcol + srow)      * IN_F + scol;
    const _Float16* bS1 = Bm + (bcol + 64 + srow) * IN_F + scol;
    const int dA = tid << 4;            // A dest base (buf0, h0, j0)
    const int dB = 32768 + (tid << 4);  // B dest base

    // --- ds_read fragment addresses (forward swizzle), buffer 0 ---
    const int rrow = lane & 15;
    const int pc0  = (((lane >> 4))     ^ (lane & 7)) << 4;  // ks=0 phys chunk
    const int pc1  = ((4 + (lane >> 4)) ^ (lane & 7)) << 4;  // ks=1 phys chunk
    int aAd0 = (wr * 128 + rrow) * 128 + pc0;
    int aAd1 = (wr * 128 + rrow) * 128 + pc1;
    int bAd0 = 32768 + (wc * 64 + rrow) * 128 + pc0;
    int bAd1 = 32768 + (wc * 64 + rrow) * 128 + pc1;

    f32x4 acc[8][4];
#pragma unroll
    for (int m = 0; m < 8; ++m)
#pragma unroll
        for (int n = 0; n < 4; ++n) acc[m][n] = (f32x4){0.f, 0.f, 0.f, 0.f};

    f16x8 aF[4][2], bF[4][2];

    // --- prologue: tile0 all 4 halves (buf0) + B0[t1] + A0[t1] (buf1) ---
    stg(aS0, 0, smem, dA);
    stg(aS1, 0, smem, dA + 8192);
    stg(aS0 + HOFF, 0, smem, dA + 16384);
    stg(aS1 + HOFF, 0, smem, dA + 16384 + 8192);
    stg(bS0, 0, smem, dB);
    stg(bS1, 0, smem, dB + 8192);
    stg(bS0 + HOFF, 0, smem, dB + 16384);
    stg(bS1 + HOFF, 0, smem, dB + 16384 + 8192);
    stg(bS0, BK, smem, 65536 + dB);
    stg(bS1, BK, smem, 65536 + dB + 8192);
    stg(aS0, BK, smem, 65536 + dA);
    stg(aS1, BK, smem, 65536 + dA + 8192);
    asm volatile("s_waitcnt vmcnt(4)" ::: "memory");   // tile0 landed; 2 half-tiles in flight
    __builtin_amdgcn_sched_barrier(0);
    __builtin_amdgcn_s_barrier();
    __builtin_amdgcn_sched_barrier(0);

    for (int kt = 0; kt < NTK; ++kt) {
        // ================= phase 0: q(m0-3, n0-1); stage A1[kt+1] =========
        aF[0][0] = *(const f16x8*)(smem + aAd0);
        aF[0][1] = *(const f16x8*)(smem + aAd1);
        aF[1][0] = *(const f16x8*)(smem + aAd0 + 2048);
        aF[1][1] = *(const f16x8*)(smem + aAd1 + 2048);
        aF[2][0] = *(const f16x8*)(smem + aAd0 + 4096);
        aF[2][1] = *(const f16x8*)(smem + aAd1 + 4096);
        aF[3][0] = *(const f16x8*)(smem + aAd0 + 6144);
        aF[3][1] = *(const f16x8*)(smem + aAd1 + 6144);
        bF[0][0] = *(const f16x8*)(smem + bAd0);
        bF[0][1] = *(const f16x8*)(smem + bAd1);
        bF[1][0] = *(const f16x8*)(smem + bAd0 + 2048);
        bF[1][1] = *(const f16x8*)(smem + bAd1 + 2048);
        if (kt < NTK - 1) {
            const int d  = (((kt + 1) & 1) << 16) + 16384 + (tid << 4);
            const int ke = (kt + 1) * BK;
            stg(aS0 + HOFF, ke, smem, d);
            stg(aS1 + HOFF, ke, smem, d + 8192);
        }
        __builtin_amdgcn_s_barrier();
        __builtin_amdgcn_sched_barrier(0);
        __builtin_amdgcn_s_setprio(1);
#pragma unroll
        for (int ks = 0; ks < 2; ++ks)
#pragma unroll
            for (int i = 0; i < 4; ++i)
#pragma unroll
                for (int nn = 0; nn < 2; ++nn)
                    acc[i][nn] = __builtin_amdgcn_mfma_f32_16x16x32_f16(
                        aF[i][ks], bF[nn][ks], acc[i][nn], 0, 0, 0);
        __builtin_amdgcn_s_setprio(0);
        __builtin_amdgcn_s_barrier();
        __builtin_amdgcn_sched_barrier(0);

        // ================= phase 1: q(m0-3, n2-3); stage B1[kt+1] =========
        bF[2][0] = *(const f16x8*)(smem + bAd0 + 4096);
        bF[2][1] = *(const f16x8*)(smem + bAd1 + 4096);
        bF[3][0] = *(const f16x8*)(smem + bAd0 + 6144);
        bF[3][1] = *(const f16x8*)(smem + bAd1 + 6144);
        if (kt < NTK - 1) {
            const int d  = (((kt + 1) & 1) << 16) + 32768 + 16384 + (tid << 4);
            const int ke = (kt + 1) * BK;
            stg(bS0 + HOFF, ke, smem, d);
            stg(bS1 + HOFF, ke, smem, d + 8192);
        }
        __builtin_amdgcn_s_barrier();
        __builtin_amdgcn_sched_barrier(0);
        __builtin_amdgcn_s_setprio(1);
#pragma unroll
        for (int ks = 0; ks < 2; ++ks)
#pragma unroll
            for (int i = 0; i < 4; ++i)
#pragma unroll
                for (int nn = 0; nn < 2; ++nn)
                    acc[i][2 + nn] = __builtin_amdgcn_mfma_f32_16x16x32_f16(
                        aF[i][ks], bF[2 + nn][ks], acc[i][2 + nn], 0, 0, 0);
        __builtin_amdgcn_s_setprio(0);
        __builtin_amdgcn_s_barrier();
        __builtin_amdgcn_sched_barrier(0);

        // ================= phase 2: q(m4-7, n0-1); stage B0[kt+2] =========
        aF[0][0] = *(const f16x8*)(smem + aAd0 + 8192);
        aF[0][1] = *(const f16x8*)(smem + aAd1 + 8192);
        aF[1][0] = *(const f16x8*)(smem + aAd0 + 10240);
        aF[1][1] = *(const f16x8*)(smem + aAd1 + 10240);
        aF[2][0] = *(const f16x8*)(smem + aAd0 + 12288);
        aF[2][1] = *(const f16x8*)(smem + aAd1 + 12288);
        aF[3][0] = *(const f16x8*)(smem + aAd0 + 14336);
        aF[3][1] = *(const f16x8*)(smem + aAd1 + 14336);
        if (kt < NTK - 2) {
            const int d  = ((kt & 1) << 16) + 32768 + (tid << 4);  // (kt+2)&1 == kt&1
            const int ke = (kt + 2) * BK;
            stg(bS0, ke, smem, d);
            stg(bS1, ke, smem, d + 8192);
        }
        __builtin_amdgcn_s_barrier();
        __builtin_amdgcn_sched_barrier(0);
        __builtin_amdgcn_s_setprio(1);
#pragma unroll
        for (int ks = 0; ks < 2; ++ks)
#pragma unroll
            for (int i = 0; i < 4; ++i)
#pragma unroll
                for (int nn = 0; nn < 2; ++nn)
                    acc[4 + i][nn] = __builtin_amdgcn_mfma_f32_16x16x32_f16(
                        aF[i][ks], bF[nn][ks], acc[4 + i][nn], 0, 0, 0);
        __builtin_amdgcn_s_setprio(0);
        __builtin_amdgcn_s_barrier();
        __builtin_amdgcn_sched_barrier(0);

        // ========== phase 3: q(m4-7, n2-3); stage A0[kt+2]; vmcnt ==========
        if (kt < NTK - 2) {
            const int d  = ((kt & 1) << 16) + (tid << 4);
            const int ke = (kt + 2) * BK;
            stg(aS0, ke, smem, d);
            stg(aS1, ke, smem, d + 8192);
        }
        if (kt < NTK - 2) {
            asm volatile("s_waitcnt vmcnt(4)" ::: "memory");  // tile kt+1 fully landed
        } else {
            asm volatile("s_waitcnt vmcnt(0)" ::: "memory");  // drain at stream end
        }
        __builtin_amdgcn_sched_barrier(0);
        __builtin_amdgcn_s_barrier();
        __builtin_amdgcn_sched_barrier(0);
        __builtin_amdgcn_s_setprio(1);
#pragma unroll
        for (int ks = 0; ks < 2; ++ks)
#pragma unroll
            for (int i = 0; i < 4; ++i)
#pragma unroll
                for (int nn = 0; nn < 2; ++nn)
                    acc[4 + i][2 + nn] = __builtin_amdgcn_mfma_f32_16x16x32_f16(
                        aF[i][ks], bF[2 + nn][ks], acc[4 + i][2 + nn], 0, 0, 0);
        __builtin_amdgcn_s_setprio(0);
        __builtin_amdgcn_s_barrier();
        __builtin_amdgcn_sched_barrier(0);

        aAd0 ^= 65536; aAd1 ^= 65536; bAd0 ^= 65536; bAd1 ^= 65536;
    }

    // --- epilogue: C/D layout col = lane&15, row = (lane>>4)*4 + j ---
    const int crow = (lane >> 4) << 2;
    const int ccol = lane & 15;
#pragma unroll
    for (int n = 0; n < 4; ++n) {
        const size_t col = bcol + wc * 64 + n * 16 + ccol;
        const float bv = bias[col];
#pragma unroll
        for (int m = 0; m < 8; ++m) {
            const size_t row = brow + wr * 128 + m * 16 + crow;
            float* cp = C + row * OUT_F + col;
#pragma unroll
            for (int j = 0; j < 4; ++j)
                cp[(size_t)j * OUT_F] = acc[m][n][j] + bv;
        }
    }
}

// ---------------------------------------------------------------------------
extern "C" void kernel_launch(void* const* d_in, const int* in_sizes, int n_in,
                              void* d_out, int out_size, void* d_ws, size_t ws_size,
                              hipStream_t stream) {
    const float* x    = (const float*)d_in[0];
    const float* hw   = (const float*)d_in[1];
    const float* hb   = (const float*)d_in[2];
    const float* xiW  = (const float*)d_in[3];
    const float* xiB  = (const float*)d_in[4];
    const int*   idxW = (const int*)d_in[5];
    const int*   idxB = (const int*)d_in[6];
    float* out = (float*)d_out;

    char* ws = (char*)d_ws;
    _Float16* Wh  = (_Float16*)ws;                                   // 32 MB
    _Float16* Xh  = (_Float16*)(ws + (size_t)32 * 1024 * 1024);      // 64 MB
    float*    bia = (float*)   (ws + (size_t)96 * 1024 * 1024);      // 16 KB

    // allow 128 KiB dynamic LDS (host-side attribute set; not a stream op)
    (void)hipFuncSetAttribute((const void*)gemm_8ph,
                              hipFuncAttributeMaxDynamicSharedMemorySize, 131072);

    build_w<<<8192, 256, 0, stream>>>(hw, xiW, idxW, (u32x4*)Wh);
    conv_x<<<16384, 256, 0, stream>>>(x, (u32x4*)Xh);
    build_bias<<<OUT_F / 256, 256, 0, stream>>>(hb, xiB, idxB, bia);
    // 32 m-tiles x 16 n-tiles = 512 blocks, 512 threads, 128KB LDS
    gemm_8ph<<<512, 512, 131072, stream>>>(Xh, Wh, bia, out);
}

// Round 3
// 360.895 us; speedup vs baseline: 1.2883x; 1.0629x over previous
//
#include <hip/hip_runtime.h>
#include <hip/hip_bf16.h>
#include <stdint.h>

#define IN_F   4096
#define OUT_F  4096
#define BATCHN 8192

#define BK   64
#define NTK  (IN_F / BK)       // 64 K-tiles
#define HOFF (128 * IN_F)      // half-tile (128 rows) offset in elements

using f32x4 = __attribute__((ext_vector_type(4))) float;
using f16x8 = __attribute__((ext_vector_type(8))) _Float16;
using i32x4 = __attribute__((ext_vector_type(4))) int;
using u32x4 = __attribute__((ext_vector_type(4))) unsigned int;

__device__ __forceinline__ void stg(const _Float16* src, int kelem, char* sm, int dstoff) {
    __builtin_amdgcn_global_load_lds(
        (const __attribute__((address_space(1))) void*)(src + kelem),
        (__attribute__((address_space(3))) void*)(sm + dstoff), 16, 0, 0);
}

__device__ __forceinline__ u32x4 pack8_f16(const float* v) {
    union { _Float16 h[8]; u32x4 u; } p;
#pragma unroll
    for (int i = 0; i < 8; ++i) p.h[i] = (_Float16)v[i];
    return p.u;
}

// ---------------------------------------------------------------------------
// Kernel 1: W[o][i] = h_weight[idxW[o][i]] * xiW[o][i]  -> fp16, row-major
// ---------------------------------------------------------------------------
__global__ __launch_bounds__(256) void build_w(const float* __restrict__ hw,
                                               const float* __restrict__ xi,
                                               const int*   __restrict__ idx,
                                               u32x4* __restrict__ Wh) {
    size_t t = (size_t)blockIdx.x * 256 + threadIdx.x;
    size_t base = t * 8;
    i32x4 i0 = *(const i32x4*)(idx + base);
    i32x4 i1 = *(const i32x4*)(idx + base + 4);
    f32x4 s0 = *(const f32x4*)(xi + base);
    f32x4 s1 = *(const f32x4*)(xi + base + 4);
    float v[8];
    v[0] = hw[i0[0]] * s0[0];
    v[1] = hw[i0[1]] * s0[1];
    v[2] = hw[i0[2]] * s0[2];
    v[3] = hw[i0[3]] * s0[3];
    v[4] = hw[i1[0]] * s1[0];
    v[5] = hw[i1[1]] * s1[1];
    v[6] = hw[i1[2]] * s1[2];
    v[7] = hw[i1[3]] * s1[3];
    Wh[t] = pack8_f16(v);
}

// ---------------------------------------------------------------------------
// Kernel 2: x fp32 -> fp16
// ---------------------------------------------------------------------------
__global__ __launch_bounds__(256) void conv_x(const float* __restrict__ x,
                                              u32x4* __restrict__ Xh) {
    size_t t = (size_t)blockIdx.x * 256 + threadIdx.x;
    size_t base = t * 8;
    f32x4 a = *(const f32x4*)(x + base);
    f32x4 b = *(const f32x4*)(x + base + 4);
    float v[8] = {a[0], a[1], a[2], a[3], b[0], b[1], b[2], b[3]};
    Xh[t] = pack8_f16(v);
}

// ---------------------------------------------------------------------------
// Kernel 3: bias[o] = h_bias[idxB[o]] * xiB[o]
// ---------------------------------------------------------------------------
__global__ __launch_bounds__(256) void build_bias(const float* __restrict__ hb,
                                                  const float* __restrict__ xib,
                                                  const int*   __restrict__ idxb,
                                                  float* __restrict__ bias) {
    int o = blockIdx.x * 256 + threadIdx.x;
    if (o < OUT_F) bias[o] = hb[idxb[o]] * xib[o];
}

// ---------------------------------------------------------------------------
// Kernel 4: 256x256x64 GEMM, fp16 MFMA, fp32 out + bias.
// 4 phases/K-tile; depth-3 staging pipeline (vmcnt(6) once per tile):
//   ph0: read aFlo(8)+bF(8); stage T+1.A1 | MFMA acc[0..3][0..1]
//   ph1: read aFhi(8);       stage T+2.B0 | MFMA acc[0..3][2..3]
//   ph2:                     stage T+2.B1 | MFMA acc[4..7][0..1]
//   ph3:                     stage T+2.A0 | vmcnt(6) | MFMA acc[4..7][2..3]
// WAR ledger: B halves of current buf last read ph0 (free after ph0 end bar);
// A halves last read ph1 (free after ph1 end bar). T+2.B0@ph1, B1@ph2,
// A0@ph3 all legal. T+1.A1 goes to the other buffer (free anytime).
// Swizzle: phys = linear ^ ((row&7)<<4), applied inverse on global source
// (gload_lds linear dest) and forward on ds_read addrs.
// ---------------------------------------------------------------------------
__global__ __launch_bounds__(512, 2) void gemm_8ph(const _Float16* __restrict__ A,  // [BATCHN][IN_F]
                                                   const _Float16* __restrict__ Bm, // [OUT_F][IN_F]
                                                   const float*    __restrict__ bias,
                                                   float*          __restrict__ C) {
    extern __shared__ char smem[];
    const int tid  = threadIdx.x;
    const int lane = tid & 63;
    const int wave = tid >> 6;
    const int wr   = wave >> 2;  // 0..1 -> rows wr*128
    const int wc   = wave & 3;   // 0..3 -> cols wc*64

    // 8x8 per-XCD chunking: each XCD owns an 8m x 8n block of tiles ->
    // 8 A-panels + 8 B-panels per XCD L2 (vs 32 A-panels before).
    const int bid   = blockIdx.x;
    const int xcd   = bid & 7;
    const int local = bid >> 3;             // 0..63
    const int m_idx = (xcd & 3) * 8 + (local & 7);   // 0..31
    const int n_idx = (xcd >> 2) * 8 + (local >> 3); // 0..15
    const size_t brow = (size_t)m_idx * 256;
    const size_t bcol = (size_t)n_idx * 256;

    // --- staging source addresses (inverse-swizzled global side) ---
    const int srow = tid >> 3;                       // 0..63
    const int scol = ((tid & 7) ^ (srow & 7)) << 3;  // element col (inverse XOR)
    const _Float16* aS0 = A  + (brow + srow)      * IN_F + scol;  // j=0 rows
    const _Float16* aS1 = A  + (brow + 64 + srow) * IN_F + scol;  // j=1 rows
    const _Float16* bS0 = Bm + (bcol + srow)      * IN_F + scol;
    const _Float16* bS1 = Bm + (bcol + 64 + srow) * IN_F + scol;
    const int dA = tid << 4;            // A dest base (buf0, h0, j0)
    const int dB = 32768 + (tid << 4);  // B dest base

    // --- ds_read fragment addresses (forward swizzle), buffer 0 ---
    const int rrow = lane & 15;
    const int pc0  = (((lane >> 4))     ^ (lane & 7)) << 4;  // ks=0 phys chunk
    const int pc1  = ((4 + (lane >> 4)) ^ (lane & 7)) << 4;  // ks=1 phys chunk
    int aAd0 = (wr * 128 + rrow) * 128 + pc0;
    int aAd1 = (wr * 128 + rrow) * 128 + pc1;
    int bAd0 = 32768 + (wc * 64 + rrow) * 128 + pc0;
    int bAd1 = 32768 + (wc * 64 + rrow) * 128 + pc1;

    f32x4 acc[8][4];
#pragma unroll
    for (int m = 0; m < 8; ++m)
#pragma unroll
        for (int n = 0; n < 4; ++n) acc[m][n] = (f32x4){0.f, 0.f, 0.f, 0.f};

    f16x8 aFlo[4][2], aFhi[4][2], bF[4][2];

    // --- prologue: T0 all 4 halves (buf0); T1.B0,B1,A0 (buf1) ---
    stg(aS0, 0, smem, dA);
    stg(aS1, 0, smem, dA + 8192);
    stg(aS0 + HOFF, 0, smem, dA + 16384);
    stg(aS1 + HOFF, 0, smem, dA + 16384 + 8192);
    stg(bS0, 0, smem, dB);
    stg(bS1, 0, smem, dB + 8192);
    stg(bS0 + HOFF, 0, smem, dB + 16384);
    stg(bS1 + HOFF, 0, smem, dB + 16384 + 8192);
    stg(bS0, BK, smem, 65536 + dB);
    stg(bS1, BK, smem, 65536 + dB + 8192);
    stg(bS0 + HOFF, BK, smem, 65536 + dB + 16384);
    stg(bS1 + HOFF, BK, smem, 65536 + dB + 16384 + 8192);
    stg(aS0, BK, smem, 65536 + dA);
    stg(aS1, BK, smem, 65536 + dA + 8192);
    asm volatile("s_waitcnt vmcnt(6)" ::: "memory");   // T0 landed; T1.{B0,B1,A0} in flight
    __builtin_amdgcn_sched_barrier(0);
    __builtin_amdgcn_s_barrier();
    __builtin_amdgcn_sched_barrier(0);

    for (int kt = 0; kt < NTK; ++kt) {
        const int cur = (kt & 1) << 16;         // current buffer base
        const int nxt = cur ^ 65536;            // next-tile buffer base

        // ===== phase 0: read aFlo + ALL bF; stage T+1.A1; MFMA q(m0-3,n0-1)
#pragma unroll
        for (int i = 0; i < 4; ++i) {
            aFlo[i][0] = *(const f16x8*)(smem + aAd0 + i * 2048);
            aFlo[i][1] = *(const f16x8*)(smem + aAd1 + i * 2048);
        }
#pragma unroll
        for (int n = 0; n < 4; ++n) {
            bF[n][0] = *(const f16x8*)(smem + bAd0 + n * 2048);
            bF[n][1] = *(const f16x8*)(smem + bAd1 + n * 2048);
        }
        if (kt < NTK - 1) {  // last half of tile kt+1 -> other buffer
            const int ke = (kt + 1) * BK;
            stg(aS0 + HOFF, ke, smem, nxt + dA + 16384);
            stg(aS1 + HOFF, ke, smem, nxt + dA + 16384 + 8192);
        }
        __builtin_amdgcn_s_barrier();
        __builtin_amdgcn_sched_barrier(0);
        __builtin_amdgcn_s_setprio(1);
#pragma unroll
        for (int ks = 0; ks < 2; ++ks)
#pragma unroll
            for (int i = 0; i < 4; ++i)
#pragma unroll
                for (int nn = 0; nn < 2; ++nn)
                    acc[i][nn] = __builtin_amdgcn_mfma_f32_16x16x32_f16(
                        aFlo[i][ks], bF[nn][ks], acc[i][nn], 0, 0, 0);
        __builtin_amdgcn_s_setprio(0);
        __builtin_amdgcn_s_barrier();
        __builtin_amdgcn_sched_barrier(0);

        // ===== phase 1: read aFhi; stage T+2.B0 (cur buf); MFMA q(m0-3,n2-3)
#pragma unroll
        for (int i = 0; i < 4; ++i) {
            aFhi[i][0] = *(const f16x8*)(smem + aAd0 + 8192 + i * 2048);
            aFhi[i][1] = *(const f16x8*)(smem + aAd1 + 8192 + i * 2048);
        }
        if (kt < NTK - 2) {
            const int ke = (kt + 2) * BK;
            stg(bS0, ke, smem, cur + dB);
            stg(bS1, ke, smem, cur + dB + 8192);
        }
        __builtin_amdgcn_s_barrier();
        __builtin_amdgcn_sched_barrier(0);
        __builtin_amdgcn_s_setprio(1);
#pragma unroll
        for (int ks = 0; ks < 2; ++ks)
#pragma unroll
            for (int i = 0; i < 4; ++i)
#pragma unroll
                for (int nn = 0; nn < 2; ++nn)
                    acc[i][2 + nn] = __builtin_amdgcn_mfma_f32_16x16x32_f16(
                        aFlo[i][ks], bF[2 + nn][ks], acc[i][2 + nn], 0, 0, 0);
        __builtin_amdgcn_s_setprio(0);
        __builtin_amdgcn_s_barrier();
        __builtin_amdgcn_sched_barrier(0);

        // ===== phase 2: stage T+2.B1 (cur buf); MFMA q(m4-7,n0-1)
        if (kt < NTK - 2) {
            const int ke = (kt + 2) * BK;
            stg(bS0 + HOFF, ke, smem, cur + dB + 16384);
            stg(bS1 + HOFF, ke, smem, cur + dB + 16384 + 8192);
        }
        __builtin_amdgcn_s_barrier();
        __builtin_amdgcn_sched_barrier(0);
        __builtin_amdgcn_s_setprio(1);
#pragma unroll
        for (int ks = 0; ks < 2; ++ks)
#pragma unroll
            for (int i = 0; i < 4; ++i)
#pragma unroll
                for (int nn = 0; nn < 2; ++nn)
                    acc[4 + i][nn] = __builtin_amdgcn_mfma_f32_16x16x32_f16(
                        aFhi[i][ks], bF[nn][ks], acc[4 + i][nn], 0, 0, 0);
        __builtin_amdgcn_s_setprio(0);
        __builtin_amdgcn_s_barrier();
        __builtin_amdgcn_sched_barrier(0);

        // ===== phase 3: stage T+2.A0 (cur buf); vmcnt(6); MFMA q(m4-7,n2-3)
        if (kt < NTK - 2) {
            const int ke = (kt + 2) * BK;
            stg(aS0, ke, smem, cur + dA);
            stg(aS1, ke, smem, cur + dA + 8192);
            asm volatile("s_waitcnt vmcnt(6)" ::: "memory");  // T+1 fully landed
        } else {
            asm volatile("s_waitcnt vmcnt(0)" ::: "memory");  // drain at stream end
        }
        __builtin_amdgcn_sched_barrier(0);
        __builtin_amdgcn_s_barrier();
        __builtin_amdgcn_sched_barrier(0);
        __builtin_amdgcn_s_setprio(1);
#pragma unroll
        for (int ks = 0; ks < 2; ++ks)
#pragma unroll
            for (int i = 0; i < 4; ++i)
#pragma unroll
                for (int nn = 0; nn < 2; ++nn)
                    acc[4 + i][2 + nn] = __builtin_amdgcn_mfma_f32_16x16x32_f16(
                        aFhi[i][ks], bF[2 + nn][ks], acc[4 + i][2 + nn], 0, 0, 0);
        __builtin_amdgcn_s_setprio(0);
        __builtin_amdgcn_s_barrier();
        __builtin_amdgcn_sched_barrier(0);

        aAd0 ^= 65536; aAd1 ^= 65536; bAd0 ^= 65536; bAd1 ^= 65536;
    }

    // --- epilogue: C/D layout col = lane&15, row = (lane>>4)*4 + j ---
    const int crow = (lane >> 4) << 2;
    const int ccol = lane & 15;
#pragma unroll
    for (int n = 0; n < 4; ++n) {
        const size_t col = bcol + wc * 64 + n * 16 + ccol;
        const float bv = bias[col];
#pragma unroll
        for (int m = 0; m < 8; ++m) {
            const size_t row = brow + wr * 128 + m * 16 + crow;
            float* cp = C + row * OUT_F + col;
#pragma unroll
            for (int j = 0; j < 4; ++j)
                cp[(size_t)j * OUT_F] = acc[m][n][j] + bv;
        }
    }
}

// ---------------------------------------------------------------------------
extern "C" void kernel_launch(void* const* d_in, const int* in_sizes, int n_in,
                              void* d_out, int out_size, void* d_ws, size_t ws_size,
                              hipStream_t stream) {
    const float* x    = (const float*)d_in[0];
    const float* hw   = (const float*)d_in[1];
    const float* hb   = (const float*)d_in[2];
    const float* xiW  = (const float*)d_in[3];
    const float* xiB  = (const float*)d_in[4];
    const int*   idxW = (const int*)d_in[5];
    const int*   idxB = (const int*)d_in[6];
    float* out = (float*)d_out;

    char* ws = (char*)d_ws;
    _Float16* Wh  = (_Float16*)ws;                                   // 32 MB
    _Float16* Xh  = (_Float16*)(ws + (size_t)32 * 1024 * 1024);      // 64 MB
    float*    bia = (float*)   (ws + (size_t)96 * 1024 * 1024);      // 16 KB

    (void)hipFuncSetAttribute((const void*)gemm_8ph,
                              hipFuncAttributeMaxDynamicSharedMemorySize, 131072);

    build_w<<<8192, 256, 0, stream>>>(hw, xiW, idxW, (u32x4*)Wh);
    conv_x<<<16384, 256, 0, stream>>>(x, (u32x4*)Xh);
    build_bias<<<OUT_F / 256, 256, 0, stream>>>(hb, xiB, idxB, bia);
    gemm_8ph<<<512, 512, 131072, stream>>>(Xh, Wh, bia, out);
}

// Round 4
// 352.263 us; speedup vs baseline: 1.3199x; 1.0245x over previous
//
#include <hip/hip_runtime.h>
#include <hip/hip_bf16.h>
#include <stdint.h>

#define IN_F   4096
#define OUT_F  4096
#define BATCHN 8192

#define BK   64
#define NTK  (IN_F / BK)       // 64 K-tiles
#define HOFF (128 * IN_F)      // half-tile (128 rows) offset in elements

using f32x4 = __attribute__((ext_vector_type(4))) float;
using f16x8 = __attribute__((ext_vector_type(8))) _Float16;
using i32x4 = __attribute__((ext_vector_type(4))) int;
using u32x4 = __attribute__((ext_vector_type(4))) unsigned int;

__device__ __forceinline__ void stg(const _Float16* src, int kelem, char* sm, int dstoff) {
    __builtin_amdgcn_global_load_lds(
        (const __attribute__((address_space(1))) void*)(src + kelem),
        (__attribute__((address_space(3))) void*)(sm + dstoff), 16, 0, 0);
}

__device__ __forceinline__ u32x4 pack8_f16(const float* v) {
    union { _Float16 h[8]; u32x4 u; } p;
#pragma unroll
    for (int i = 0; i < 8; ++i) p.h[i] = (_Float16)v[i];
    return p.u;
}

// ---------------------------------------------------------------------------
// Fused prep: blocks [0,8192): build W (fp16); [8192,24576): convert x;
// [24576,24592): bias.  One dispatch instead of three.
// ---------------------------------------------------------------------------
__global__ __launch_bounds__(256) void prep(const float* __restrict__ hw,
                                            const float* __restrict__ xiW,
                                            const int*   __restrict__ idxW,
                                            u32x4* __restrict__ Wh,
                                            const float* __restrict__ x,
                                            u32x4* __restrict__ Xh,
                                            const float* __restrict__ hb,
                                            const float* __restrict__ xiB,
                                            const int*   __restrict__ idxB,
                                            float* __restrict__ bias) {
    const int b = blockIdx.x;
    if (b < 8192) {
        size_t t = (size_t)b * 256 + threadIdx.x;
        size_t base = t * 8;
        i32x4 i0 = *(const i32x4*)(idxW + base);
        i32x4 i1 = *(const i32x4*)(idxW + base + 4);
        f32x4 s0 = *(const f32x4*)(xiW + base);
        f32x4 s1 = *(const f32x4*)(xiW + base + 4);
        float v[8];
        v[0] = hw[i0[0]] * s0[0];
        v[1] = hw[i0[1]] * s0[1];
        v[2] = hw[i0[2]] * s0[2];
        v[3] = hw[i0[3]] * s0[3];
        v[4] = hw[i1[0]] * s1[0];
        v[5] = hw[i1[1]] * s1[1];
        v[6] = hw[i1[2]] * s1[2];
        v[7] = hw[i1[3]] * s1[3];
        Wh[t] = pack8_f16(v);
    } else if (b < 24576) {
        size_t t = (size_t)(b - 8192) * 256 + threadIdx.x;
        size_t base = t * 8;
        f32x4 a = *(const f32x4*)(x + base);
        f32x4 c = *(const f32x4*)(x + base + 4);
        float v[8] = {a[0], a[1], a[2], a[3], c[0], c[1], c[2], c[3]};
        Xh[t] = pack8_f16(v);
    } else {
        int o = (b - 24576) * 256 + threadIdx.x;
        if (o < OUT_F) bias[o] = hb[idxB[o]] * xiB[o];
    }
}

// ---------------------------------------------------------------------------
// 256x256x64 GEMM, fp16 MFMA, fp32 out + bias.
// Reads per phase: 12/4/8/0 (each operand lands in the phase whose MFMA
// first needs it; ks=0 issued before ks=1 so compiler fine-lgkmcnt hides
// the ks=1 drain under the ks=0 MFMA cluster).
//   ph0: rd aFlo+bF01; stage T+1.A1 (nxt) | MFMA Q00 acc[0..3][0..1]
//   ph1: rd bF23                          | MFMA Q01 acc[0..3][2..3]
//   ph2: rd aFhi;      stage T+2.B0 (cur) | MFMA Q10 acc[4..7][0..1]
//   ph3:               stage T+2.B1+A0; vmcnt(6) | MFMA Q11 acc[4..7][2..3]
// Region-free points: B halves after ph1 (bF23), A halves after ph2 (aFhi).
// Stage legality: T+2.B0@ph2, B1/A0@ph3 (cur, after free+barrier);
// T+1.A1@ph0 (nxt; its A last read T-1.ph2). vmcnt(6)@ph3 retires exactly
// T+1.{B0(T-1.ph2), B1+A0(T-1.ph3), A1(T.ph0)}; leaves T+2.{B0,B1,A0}=6.
// Swizzle: phys = linear ^ ((row&7)<<4), inverse on global src, fwd on reads.
// ---------------------------------------------------------------------------
__global__ __launch_bounds__(512, 2) void gemm_8ph(const _Float16* __restrict__ A,  // [BATCHN][IN_F]
                                                   const _Float16* __restrict__ Bm, // [OUT_F][IN_F]
                                                   const float*    __restrict__ bias,
                                                   float*          __restrict__ C) {
    extern __shared__ char smem[];
    const int tid  = threadIdx.x;
    const int lane = tid & 63;
    const int wave = tid >> 6;
    const int wr   = wave >> 2;  // 0..1 -> rows wr*128
    const int wc   = wave & 3;   // 0..3 -> cols wc*64

    // 8x8 per-XCD chunking: each XCD touches 8 A-panels + 8 B-panels.
    const int bid   = blockIdx.x;
    const int xcd   = bid & 7;
    const int local = bid >> 3;             // 0..63
    const int m_idx = (xcd & 3) * 8 + (local & 7);   // 0..31
    const int n_idx = (xcd >> 2) * 8 + (local >> 3); // 0..15
    const size_t brow = (size_t)m_idx * 256;
    const size_t bcol = (size_t)n_idx * 256;

    // --- staging source addresses (inverse-swizzled global side) ---
    const int srow = tid >> 3;                       // 0..63
    const int scol = ((tid & 7) ^ (srow & 7)) << 3;  // element col (inverse XOR)
    const _Float16* aS0 = A  + (brow + srow)      * IN_F + scol;
    const _Float16* aS1 = A  + (brow + 64 + srow) * IN_F + scol;
    const _Float16* bS0 = Bm + (bcol + srow)      * IN_F + scol;
    const _Float16* bS1 = Bm + (bcol + 64 + srow) * IN_F + scol;
    const int dA = tid << 4;            // A dest base (buf0, h0, j0)
    const int dB = 32768 + (tid << 4);  // B dest base

    // --- ds_read fragment addresses (forward swizzle), buffer 0 ---
    const int rrow = lane & 15;
    const int pc0  = (((lane >> 4))     ^ (lane & 7)) << 4;  // ks=0 phys chunk
    const int pc1  = ((4 + (lane >> 4)) ^ (lane & 7)) << 4;  // ks=1 phys chunk
    int aAd0 = (wr * 128 + rrow) * 128 + pc0;
    int aAd1 = (wr * 128 + rrow) * 128 + pc1;
    int bAd0 = 32768 + (wc * 64 + rrow) * 128 + pc0;
    int bAd1 = 32768 + (wc * 64 + rrow) * 128 + pc1;

    f32x4 acc[8][4];
#pragma unroll
    for (int m = 0; m < 8; ++m)
#pragma unroll
        for (int n = 0; n < 4; ++n) acc[m][n] = (f32x4){0.f, 0.f, 0.f, 0.f};

    f16x8 aFlo[4][2], aFhi[4][2], bF[4][2];

    // --- prologue: T0 all 4 halves (buf0); T1.{B0,B1,A0} (buf1) ---
    stg(aS0, 0, smem, dA);
    stg(aS1, 0, smem, dA + 8192);
    stg(aS0 + HOFF, 0, smem, dA + 16384);
    stg(aS1 + HOFF, 0, smem, dA + 16384 + 8192);
    stg(bS0, 0, smem, dB);
    stg(bS1, 0, smem, dB + 8192);
    stg(bS0 + HOFF, 0, smem, dB + 16384);
    stg(bS1 + HOFF, 0, smem, dB + 16384 + 8192);
    stg(bS0, BK, smem, 65536 + dB);
    stg(bS1, BK, smem, 65536 + dB + 8192);
    stg(bS0 + HOFF, BK, smem, 65536 + dB + 16384);
    stg(bS1 + HOFF, BK, smem, 65536 + dB + 16384 + 8192);
    stg(aS0, BK, smem, 65536 + dA);
    stg(aS1, BK, smem, 65536 + dA + 8192);
    asm volatile("s_waitcnt vmcnt(6)" ::: "memory");   // T0 landed
    __builtin_amdgcn_sched_barrier(0);
    __builtin_amdgcn_s_barrier();
    __builtin_amdgcn_sched_barrier(0);

    for (int kt = 0; kt < NTK; ++kt) {
        const int cur = (kt & 1) << 16;         // current buffer base
        const int nxt = cur ^ 65536;            // next-tile buffer base

        // ===== ph0: rd aFlo(8)+bF01(4) ks0-first; stage T+1.A1; MFMA Q00
#pragma unroll
        for (int i = 0; i < 4; ++i) aFlo[i][0] = *(const f16x8*)(smem + aAd0 + i * 2048);
        bF[0][0] = *(const f16x8*)(smem + bAd0);
        bF[1][0] = *(const f16x8*)(smem + bAd0 + 2048);
#pragma unroll
        for (int i = 0; i < 4; ++i) aFlo[i][1] = *(const f16x8*)(smem + aAd1 + i * 2048);
        bF[0][1] = *(const f16x8*)(smem + bAd1);
        bF[1][1] = *(const f16x8*)(smem + bAd1 + 2048);
        if (kt < NTK - 1) {
            const int ke = (kt + 1) * BK;
            stg(aS0 + HOFF, ke, smem, nxt + dA + 16384);
            stg(aS1 + HOFF, ke, smem, nxt + dA + 16384 + 8192);
        }
        __builtin_amdgcn_s_barrier();
        __builtin_amdgcn_sched_barrier(0);
        __builtin_amdgcn_s_setprio(1);
#pragma unroll
        for (int ks = 0; ks < 2; ++ks)
#pragma unroll
            for (int i = 0; i < 4; ++i)
#pragma unroll
                for (int nn = 0; nn < 2; ++nn)
                    acc[i][nn] = __builtin_amdgcn_mfma_f32_16x16x32_f16(
                        aFlo[i][ks], bF[nn][ks], acc[i][nn], 0, 0, 0);
        __builtin_amdgcn_s_setprio(0);
        __builtin_amdgcn_s_barrier();
        __builtin_amdgcn_sched_barrier(0);

        // ===== ph1: rd bF23(4); MFMA Q01
        bF[2][0] = *(const f16x8*)(smem + bAd0 + 4096);
        bF[3][0] = *(const f16x8*)(smem + bAd0 + 6144);
        bF[2][1] = *(const f16x8*)(smem + bAd1 + 4096);
        bF[3][1] = *(const f16x8*)(smem + bAd1 + 6144);
        __builtin_amdgcn_s_barrier();
        __builtin_amdgcn_sched_barrier(0);
        __builtin_amdgcn_s_setprio(1);
#pragma unroll
        for (int ks = 0; ks < 2; ++ks)
#pragma unroll
            for (int i = 0; i < 4; ++i)
#pragma unroll
                for (int nn = 0; nn < 2; ++nn)
                    acc[i][2 + nn] = __builtin_amdgcn_mfma_f32_16x16x32_f16(
                        aFlo[i][ks], bF[2 + nn][ks], acc[i][2 + nn], 0, 0, 0);
        __builtin_amdgcn_s_setprio(0);
        __builtin_amdgcn_s_barrier();
        __builtin_amdgcn_sched_barrier(0);

        // ===== ph2: rd aFhi(8) ks0-first; stage T+2.B0; MFMA Q10
#pragma unroll
        for (int i = 0; i < 4; ++i) aFhi[i][0] = *(const f16x8*)(smem + aAd0 + 8192 + i * 2048);
#pragma unroll
        for (int i = 0; i < 4; ++i) aFhi[i][1] = *(const f16x8*)(smem + aAd1 + 8192 + i * 2048);
        if (kt < NTK - 2) {
            const int ke = (kt + 2) * BK;
            stg(bS0, ke, smem, cur + dB);
            stg(bS1, ke, smem, cur + dB + 8192);
        }
        __builtin_amdgcn_s_barrier();
        __builtin_amdgcn_sched_barrier(0);
        __builtin_amdgcn_s_setprio(1);
#pragma unroll
        for (int ks = 0; ks < 2; ++ks)
#pragma unroll
            for (int i = 0; i < 4; ++i)
#pragma unroll
                for (int nn = 0; nn < 2; ++nn)
                    acc[4 + i][nn] = __builtin_amdgcn_mfma_f32_16x16x32_f16(
                        aFhi[i][ks], bF[nn][ks], acc[4 + i][nn], 0, 0, 0);
        __builtin_amdgcn_s_setprio(0);
        __builtin_amdgcn_s_barrier();
        __builtin_amdgcn_sched_barrier(0);

        // ===== ph3: stage T+2.B1 + T+2.A0; vmcnt(6); MFMA Q11
        if (kt < NTK - 2) {
            const int ke = (kt + 2) * BK;
            stg(bS0 + HOFF, ke, smem, cur + dB + 16384);
            stg(bS1 + HOFF, ke, smem, cur + dB + 16384 + 8192);
            stg(aS0, ke, smem, cur + dA);
            stg(aS1, ke, smem, cur + dA + 8192);
            asm volatile("s_waitcnt vmcnt(6)" ::: "memory");  // T+1 fully landed
        } else {
            asm volatile("s_waitcnt vmcnt(0)" ::: "memory");  // drain at stream end
        }
        __builtin_amdgcn_sched_barrier(0);
        __builtin_amdgcn_s_barrier();
        __builtin_amdgcn_sched_barrier(0);
        __builtin_amdgcn_s_setprio(1);
#pragma unroll
        for (int ks = 0; ks < 2; ++ks)
#pragma unroll
            for (int i = 0; i < 4; ++i)
#pragma unroll
                for (int nn = 0; nn < 2; ++nn)
                    acc[4 + i][2 + nn] = __builtin_amdgcn_mfma_f32_16x16x32_f16(
                        aFhi[i][ks], bF[2 + nn][ks], acc[4 + i][2 + nn], 0, 0, 0);
        __builtin_amdgcn_s_setprio(0);
        __builtin_amdgcn_s_barrier();
        __builtin_amdgcn_sched_barrier(0);

        aAd0 ^= 65536; aAd1 ^= 65536; bAd0 ^= 65536; bAd1 ^= 65536;
    }

    // --- epilogue: C/D layout col = lane&15, row = (lane>>4)*4 + j ---
    const int crow = (lane >> 4) << 2;
    const int ccol = lane & 15;
#pragma unroll
    for (int n = 0; n < 4; ++n) {
        const size_t col = bcol + wc * 64 + n * 16 + ccol;
        const float bv = bias[col];
#pragma unroll
        for (int m = 0; m < 8; ++m) {
            const size_t row = brow + wr * 128 + m * 16 + crow;
            float* cp = C + row * OUT_F + col;
#pragma unroll
            for (int j = 0; j < 4; ++j)
                cp[(size_t)j * OUT_F] = acc[m][n][j] + bv;
        }
    }
}

// ---------------------------------------------------------------------------
extern "C" void kernel_launch(void* const* d_in, const int* in_sizes, int n_in,
                              void* d_out, int out_size, void* d_ws, size_t ws_size,
                              hipStream_t stream) {
    const float* x    = (const float*)d_in[0];
    const float* hw   = (const float*)d_in[1];
    const float* hb   = (const float*)d_in[2];
    const float* xiW  = (const float*)d_in[3];
    const float* xiB  = (const float*)d_in[4];
    const int*   idxW = (const int*)d_in[5];
    const int*   idxB = (const int*)d_in[6];
    float* out = (float*)d_out;

    char* ws = (char*)d_ws;
    _Float16* Wh  = (_Float16*)ws;                                   // 32 MB
    _Float16* Xh  = (_Float16*)(ws + (size_t)32 * 1024 * 1024);      // 64 MB
    float*    bia = (float*)   (ws + (size_t)96 * 1024 * 1024);      // 16 KB

    (void)hipFuncSetAttribute((const void*)gemm_8ph,
                              hipFuncAttributeMaxDynamicSharedMemorySize, 131072);

    prep<<<24592, 256, 0, stream>>>(hw, xiW, idxW, (u32x4*)Wh,
                                    x, (u32x4*)Xh, hb, xiB, idxB, bia);
    gemm_8ph<<<512, 512, 131072, stream>>>(Xh, Wh, bia, out);
}